// Round 3
// baseline (278.373 us; speedup 1.0000x reference)
//
#include <hip/hip_runtime.h>

#define B_ 2
#define C_ 3
#define H_ 512
#define W_ 512
#define F_ 5
#define T_ 25
#define HW_ (H_ * W_)

// streaming loads: no reuse, keep them out of the way of the cached input
#define NT(p) __builtin_nontemporal_load(p)

__global__ __launch_bounds__(256) void dsepconv_kernel(
    const float* __restrict__ inp,
    const float* __restrict__ vert,
    const float* __restrict__ horz,
    const float* __restrict__ offx,
    const float* __restrict__ offy,
    const float* __restrict__ mask,
    float* __restrict__ out)
{
    const int idx = blockIdx.x * blockDim.x + threadIdx.x;  // grid is exact
    const int w = idx & (W_ - 1);
    const int h = (idx >> 9) & (H_ - 1);
    const int b = idx >> 18;

    const int hw = (h << 9) | w;

    const float* vb   = vert + b * (F_ * HW_) + hw;
    const float* hb   = horz + b * (F_ * HW_) + hw;
    const float* ob_x = offx + b * (T_ * HW_) + hw;
    const float* ob_y = offy + b * (T_ * HW_) + hw;
    const float* mb   = mask + b * (T_ * HW_) + hw;
    const float* p0   = inp  + b * (C_ * HW_);
    const float* p1   = p0 + HW_;
    const float* p2   = p0 + 2 * HW_;

    // ---- one burst: issue ALL streaming loads before any consumption ----
    float v[F_], hz[F_];
#pragma unroll
    for (int f = 0; f < F_; ++f) v[f]  = NT(vb + f * HW_);
#pragma unroll
    for (int f = 0; f < F_; ++f) hz[f] = NT(hb + f * HW_);

    float cy[T_], cx[T_], cm[T_];
#pragma unroll
    for (int t = 0; t < T_; ++t) cy[t] = NT(ob_y + t * HW_);
#pragma unroll
    for (int t = 0; t < T_; ++t) cx[t] = NT(ob_x + t * HW_);
#pragma unroll
    for (int t = 0; t < T_; ++t) cm[t] = NT(mb + t * HW_);

    float acc0 = 0.f, acc1 = 0.f, acc2 = 0.f;

    const float wf = (float)w;
    const float hf = (float)h;

#pragma unroll
    for (int t = 0; t < T_; ++t) {
        const int fy = t / F_;
        const int fx = t % F_;
        const float oy = cy[t];
        const float ox = cx[t];
        const float m  = cm[t];

        // Algebraically simplified (exact for W=H=512 powers of two):
        //   xn = clip(2*(oy+w+fx-1)/W - 1, -1, 1);  ix = ((xn+1)*W-1)/2
        // == ix = clamp(oy + w + fx - 1.5, -0.5, W-0.5)
        // faithful to reference: x coord uses offset_y, y coord uses offset_x
        float ixf = oy + (wf + (float)fx - 1.5f);
        float iyf = ox + (hf + (float)fy - 1.5f);
        ixf = fminf(fmaxf(ixf, -0.5f), (float)W_ - 0.5f);
        iyf = fminf(fmaxf(iyf, -0.5f), (float)H_ - 0.5f);

        float x0f = floorf(ixf), y0f = floorf(iyf);
        float wx1 = ixf - x0f,   wy1 = iyf - y0f;
        float wx0 = 1.0f - wx1,  wy0 = 1.0f - wy1;

        int x0 = min(max((int)x0f, 0), W_ - 1);
        int x1 = min(max((int)x0f + 1, 0), W_ - 1);
        int y0 = min(max((int)y0f, 0), H_ - 1);
        int y1 = min(max((int)y0f + 1, 0), H_ - 1);

        const float coef = v[fy] * hz[fx] * m;
        const float c00 = coef * wy0 * wx0;
        const float c01 = coef * wy0 * wx1;
        const float c10 = coef * wy1 * wx0;
        const float c11 = coef * wy1 * wx1;

        const int i00 = (y0 << 9) | x0;
        const int i01 = (y0 << 9) | x1;
        const int i10 = (y1 << 9) | x0;
        const int i11 = (y1 << 9) | x1;

        acc0 += c00 * p0[i00] + c01 * p0[i01] + c10 * p0[i10] + c11 * p0[i11];
        acc1 += c00 * p1[i00] + c01 * p1[i01] + c10 * p1[i10] + c11 * p1[i11];
        acc2 += c00 * p2[i00] + c01 * p2[i01] + c10 * p2[i10] + c11 * p2[i11];
    }

    float* ob = out + b * (C_ * HW_) + hw;
    __builtin_nontemporal_store(acc0, ob);
    __builtin_nontemporal_store(acc1, ob + HW_);
    __builtin_nontemporal_store(acc2, ob + 2 * HW_);
}

extern "C" void kernel_launch(void* const* d_in, const int* in_sizes, int n_in,
                              void* d_out, int out_size, void* d_ws, size_t ws_size,
                              hipStream_t stream) {
    const float* inp  = (const float*)d_in[0];
    const float* vert = (const float*)d_in[1];
    const float* horz = (const float*)d_in[2];
    const float* offx = (const float*)d_in[3];
    const float* offy = (const float*)d_in[4];
    const float* mask = (const float*)d_in[5];
    float* out = (float*)d_out;

    const int total = B_ * H_ * W_;
    dim3 grid(total / 256), block(256);
    hipLaunchKernelGGL(dsepconv_kernel, grid, block, 0, stream,
                       inp, vert, horz, offx, offy, mask, out);
}

// Round 4
// 244.188 us; speedup vs baseline: 1.1400x; 1.1400x over previous
//
#include <hip/hip_runtime.h>

#define B_ 2
#define C_ 3
#define H_ 512
#define W_ 512
#define F_ 5
#define T_ 25
#define HW_ (H_ * W_)

// streaming loads: no reuse, keep them out of the way of the cached input
#define NT(p) __builtin_nontemporal_load(p)

// Repack planar [B][C][H][W] -> pixel-packed [B][H][W][4] (w component = 0).
// Makes each bilinear neighbor gather a single aligned 16B load instead of
// three scattered 4B loads in different planes.
__global__ __launch_bounds__(256) void repack_kernel(
    const float* __restrict__ inp, float4* __restrict__ pk)
{
    const int idx = blockIdx.x * blockDim.x + threadIdx.x;   // over B*H*W, exact
    const int hw = idx & (HW_ - 1);
    const int b  = idx >> 18;
    const float* p = inp + b * (C_ * HW_) + hw;
    float4 v;
    v.x = p[0];
    v.y = p[HW_];
    v.z = p[2 * HW_];
    v.w = 0.0f;
    pk[idx] = v;
}

__global__ __launch_bounds__(256) void dsepconv_kernel(
    const float4* __restrict__ pk,   // packed input [B][H][W][4]
    const float* __restrict__ vert,
    const float* __restrict__ horz,
    const float* __restrict__ offx,
    const float* __restrict__ offy,
    const float* __restrict__ mask,
    float* __restrict__ out)
{
    const int idx = blockIdx.x * blockDim.x + threadIdx.x;  // grid is exact
    const int w = idx & (W_ - 1);
    const int h = (idx >> 9) & (H_ - 1);
    const int b = idx >> 18;

    const int hw = (h << 9) | w;

    const float* vb   = vert + b * (F_ * HW_) + hw;
    const float* hb   = horz + b * (F_ * HW_) + hw;
    const float* ob_x = offx + b * (T_ * HW_) + hw;
    const float* ob_y = offy + b * (T_ * HW_) + hw;
    const float* mb   = mask + b * (T_ * HW_) + hw;
    const float4* pb  = pk + b * HW_;

    float v[F_], hz[F_];
#pragma unroll
    for (int f = 0; f < F_; ++f) v[f]  = NT(vb + f * HW_);
#pragma unroll
    for (int f = 0; f < F_; ++f) hz[f] = NT(hb + f * HW_);

    float acc0 = 0.f, acc1 = 0.f, acc2 = 0.f;

    const float wf = (float)w;
    const float hf = (float)h;

    // ---- software pipeline over fy rows: prefetch row fy+1 while computing fy ----
    float cy[F_], cx[F_], cm[F_];
#pragma unroll
    for (int fx = 0; fx < F_; ++fx) {
        cy[fx] = NT(ob_y + fx * HW_);
        cx[fx] = NT(ob_x + fx * HW_);
        cm[fx] = NT(mb   + fx * HW_);
    }

#pragma unroll
    for (int fy = 0; fy < F_; ++fy) {
        float ny[F_], nx[F_], nm[F_];
        if (fy < F_ - 1) {
#pragma unroll
            for (int fx = 0; fx < F_; ++fx) {
                const int t = (fy + 1) * F_ + fx;
                ny[fx] = NT(ob_y + t * HW_);
                nx[fx] = NT(ob_x + t * HW_);
                nm[fx] = NT(mb   + t * HW_);
            }
        }

        const float vfy = v[fy];
        const float fyf = (float)fy;

#pragma unroll
        for (int fx = 0; fx < F_; ++fx) {
            const float oy = cy[fx];
            const float ox = cx[fx];
            const float m  = cm[fx];

            // Algebraically exact simplification (W=H=512):
            //   ix = clamp(oy + w + fx - 1.5, -0.5, W-0.5)
            // faithful to reference: x coord uses offset_y, y coord uses offset_x
            float ixf = oy + (wf + (float)fx - 1.5f);
            float iyf = ox + (hf + fyf       - 1.5f);
            ixf = fminf(fmaxf(ixf, -0.5f), (float)W_ - 0.5f);
            iyf = fminf(fmaxf(iyf, -0.5f), (float)H_ - 0.5f);

            float x0f = floorf(ixf), y0f = floorf(iyf);
            float wx1 = ixf - x0f,   wy1 = iyf - y0f;
            float wx0 = 1.0f - wx1,  wy0 = 1.0f - wy1;

            int x0 = min(max((int)x0f, 0), W_ - 1);
            int x1 = min(max((int)x0f + 1, 0), W_ - 1);
            int y0 = min(max((int)y0f, 0), H_ - 1);
            int y1 = min(max((int)y0f + 1, 0), H_ - 1);

            const float coef = vfy * hz[fx] * m;
            const float c00 = coef * wy0 * wx0;
            const float c01 = coef * wy0 * wx1;
            const float c10 = coef * wy1 * wx0;
            const float c11 = coef * wy1 * wx1;

            const float4 g00 = pb[(y0 << 9) | x0];
            const float4 g01 = pb[(y0 << 9) | x1];
            const float4 g10 = pb[(y1 << 9) | x0];
            const float4 g11 = pb[(y1 << 9) | x1];

            acc0 += c00 * g00.x + c01 * g01.x + c10 * g10.x + c11 * g11.x;
            acc1 += c00 * g00.y + c01 * g01.y + c10 * g10.y + c11 * g11.y;
            acc2 += c00 * g00.z + c01 * g01.z + c10 * g10.z + c11 * g11.z;
        }

        if (fy < F_ - 1) {
#pragma unroll
            for (int fx = 0; fx < F_; ++fx) {
                cy[fx] = ny[fx];
                cx[fx] = nx[fx];
                cm[fx] = nm[fx];
            }
        }
    }

    float* ob = out + b * (C_ * HW_) + hw;
    __builtin_nontemporal_store(acc0, ob);
    __builtin_nontemporal_store(acc1, ob + HW_);
    __builtin_nontemporal_store(acc2, ob + 2 * HW_);
}

extern "C" void kernel_launch(void* const* d_in, const int* in_sizes, int n_in,
                              void* d_out, int out_size, void* d_ws, size_t ws_size,
                              hipStream_t stream) {
    const float* inp  = (const float*)d_in[0];
    const float* vert = (const float*)d_in[1];
    const float* horz = (const float*)d_in[2];
    const float* offx = (const float*)d_in[3];
    const float* offy = (const float*)d_in[4];
    const float* mask = (const float*)d_in[5];
    float* out = (float*)d_out;
    float4* pk = (float4*)d_ws;   // B*H*W float4 = 8.4 MB

    const int total = B_ * H_ * W_;
    dim3 block(256), grid(total / 256);
    hipLaunchKernelGGL(repack_kernel, grid, block, 0, stream, inp, pk);
    hipLaunchKernelGGL(dsepconv_kernel, grid, block, 0, stream,
                       pk, vert, horz, offx, offy, mask, out);
}